// Round 3
// baseline (888.849 us; speedup 1.0000x reference)
//
#include <hip/hip_runtime.h>
#include <stdint.h>

#define SEQ    1024
#define NT     128
#define NBATCH 256
#define RING   4
#define SLOT_F32 (64*36)      // per-slot: 64 lanes x (32 floats + 4 pad)
#define GSTR   68             // gamma row stride in u32 (64 pairs + 4 pad)

typedef float f32x4v __attribute__((ext_vector_type(4)));
using short8 = __attribute__((ext_vector_type(8))) short;

union B8 { uint4 u4; short8 s8; };

// blocks 0..15: recurrence (16 batches each, 1 consumer wave + 3 producer waves)
// blocks 16..79: score gathers (4 batches each, 1 wave per batch)
__global__ __launch_bounds__(256, 1) void crf_kernel(
    const float* __restrict__ emissions,   // [B, SEQ, NT]
    const float* __restrict__ transitions, // [NT, NT]
    const int*   __restrict__ tags,        // [B, SEQ]
    const float* __restrict__ mask,        // [B, SEQ]
    float* __restrict__ out)               // [1]
{
    const int blk = blockIdx.x;
    const int tid = threadIdx.x;

    if (blk >= 16) {
        // ---------------- score blocks ----------------
        int b    = (blk - 16) * 4 + (tid >> 6);
        int lane = tid & 63;
        const float* emb = emissions + (size_t)b * SEQ * NT;
        const int*   tgb = tags + (size_t)b * SEQ;
        const float* mkb = mask + (size_t)b * SEQ;
        float sc = 0.f;
        for (int t = lane; t < SEQ; t += 64) {
            int   tg = tgb[t];
            float mt = mkb[t];
            sc += emb[t * NT + tg] * mt;
            if (t >= 1) sc += transitions[tgb[t - 1] * NT + tg] * mt;
        }
#pragma unroll
        for (int o = 32; o > 0; o >>= 1) sc += __shfl_down(sc, o, 64);
        if (lane == 0) atomicAdd(out, -sc * (1.0f / NBATCH));
        return;
    }

    // ---------------- recurrence blocks ----------------
    __shared__ __align__(16) float    ring[RING * SLOT_F32]; // 36864 B
    __shared__ __align__(16) uint32_t gam[16 * GSTR];        // 4352 B
    __shared__ int readyf[RING];
    __shared__ int freef[RING];

    const int wid  = tid >> 6;
    const int lane = tid & 63;
    const int bbase = blk * 16;

    if (tid == 0) {
#pragma unroll
        for (int i = 0; i < RING; ++i) { readyf[i] = -1; freef[i] = -1; }
    }
    __syncthreads();

    volatile int* vready = readyf;
    volatile int* vfree  = freef;

    if (wid != 0) {
        // ---------- producer: steps t ≡ wid-1 (mod 3), exp(E_t) -> ring ----------
        const int bp = lane >> 2;     // batch 0..15
        const int tq = lane & 3;      // tag quarter (32 tags)
        const float* ebase = emissions + ((size_t)(bbase + bp) * SEQ) * NT + tq * 32;
        for (int t = wid - 1; t < SEQ; t += 3) {
            const float* ep = ebase + (size_t)t * NT;
            float4 L[8];
#pragma unroll
            for (int u = 0; u < 8; ++u) L[u] = *(const float4*)(ep + u * 4);
#pragma unroll
            for (int u = 0; u < 8; ++u) {
                L[u].x = __expf(L[u].x); L[u].y = __expf(L[u].y);
                L[u].z = __expf(L[u].z); L[u].w = __expf(L[u].w);
            }
            int s = t & (RING - 1);
            while (vfree[s] < t - RING) { __builtin_amdgcn_s_sleep(1); }
            float* slot = ring + s * SLOT_F32;
#pragma unroll
            for (int q = 0; q < 8; ++q) {
                // consumer-lane layout: clane = 16*(q&3)+bp, slot idx = 8*tq+4*(q>>2)
                int a = (16 * (q & 3) + bp) * 36 + 8 * tq + 4 * (q >> 2);
                *(float4*)(slot + a) = L[q];
            }
            asm volatile("s_waitcnt lgkmcnt(0)");
            if (lane == 0) vready[s] = t;
        }
        return;
    }

    // ---------- consumer wave: the serial chain ----------
    const int g = lane >> 4;   // 0..3
    const int c = lane & 15;   // batch within block / MFMA column

    // A = exp(T)^T fragments, entire 128x128 in registers (bf16 pairs).
    // tile (m,kt): lane holds row j'=c (tag_new=16m+c), k = 8g+e (tag_old=32kt+8g+e)
    uint4 A[8][4];
#pragma unroll
    for (int m = 0; m < 8; ++m) {
#pragma unroll
        for (int kt = 0; kt < 4; ++kt) {
            uint32_t w0, w1, w2, w3;
#pragma unroll
            for (int ep = 0; ep < 4; ++ep) {
                int   i0 = 32 * kt + 8 * g + 2 * ep;
                int   jj = 16 * m + c;
                float f0 = __expf(transitions[i0 * NT + jj]);
                float f1 = __expf(transitions[(i0 + 1) * NT + jj]);
                uint32_t pk;
                asm("v_cvt_pk_bf16_f32 %0, %1, %2" : "=v"(pk) : "v"(f0), "v"(f1));
                if (ep == 0) w0 = pk; else if (ep == 1) w1 = pk;
                else if (ep == 2) w2 = pk; else w3 = pk;
            }
            A[m][kt] = make_uint4(w0, w1, w2, w3);
        }
    }

    const float* mbase = mask + (size_t)(bbase + c) * SEQ;
    f32x4v zero4 = {0.f, 0.f, 0.f, 0.f};

    // t = 0: gamma0 = exp(E0) straight from ring slot 0
    {
        while (vready[0] < 0) {}
        const float* slot = ring + lane * 36;
#pragma unroll
        for (int m = 0; m < 8; ++m) {
            float4 e4 = *(const float4*)(slot + 4 * m);
            uint32_t p0, p1;
            asm("v_cvt_pk_bf16_f32 %0, %1, %2" : "=v"(p0) : "v"(e4.x), "v"(e4.y));
            asm("v_cvt_pk_bf16_f32 %0, %1, %2" : "=v"(p1) : "v"(e4.z), "v"(e4.w));
            *(uint2*)&gam[c * GSTR + 8 * m + 2 * g] = make_uint2(p0, p1);
        }
        asm volatile("s_waitcnt lgkmcnt(0)");
        if (lane == 0) vfree[0] = 0;
    }
    // initial B fragments (gamma^T): lane holds col c, k = 8g+e of K-tile kt
    B8 Bf[4];
#pragma unroll
    for (int kt = 0; kt < 4; ++kt)
        Bf[kt].u4 = *(const uint4*)&gam[c * GSTR + 16 * kt + 4 * g];

    int   kSum   = 0;
    float mt_cur = mbase[1];

    for (int t = 1; t < SEQ; ++t) {
        int s = t & (RING - 1);
        while (vready[s] < t) {}
        const float* slot = ring + s * SLOT_F32 + lane * 36;

        float mt = mt_cur;
        mt_cur = mbase[t + 1 < SEQ ? t + 1 : SEQ - 1];

        // 32 MFMAs: D[tag_new x batch] += expT^T * gamma^T
        f32x4v acc[8];
#pragma unroll
        for (int m = 0; m < 8; ++m) {
            B8 a0, a1, a2, a3;
            a0.u4 = A[m][0]; a1.u4 = A[m][1]; a2.u4 = A[m][2]; a3.u4 = A[m][3];
            f32x4v t0 = __builtin_amdgcn_mfma_f32_16x16x32_bf16(a0.s8, Bf[0].s8, zero4, 0, 0, 0);
            t0        = __builtin_amdgcn_mfma_f32_16x16x32_bf16(a1.s8, Bf[1].s8, t0,   0, 0, 0);
            t0        = __builtin_amdgcn_mfma_f32_16x16x32_bf16(a2.s8, Bf[2].s8, t0,   0, 0, 0);
            acc[m]    = __builtin_amdgcn_mfma_f32_16x16x32_bf16(a3.s8, Bf[3].s8, t0,   0, 0, 0);
        }

        // per-batch exact pow-2 rescale every 4 steps (c0 = new gamma[tag0])
        bool  resc = ((t & 3) == 0);
        float rc   = 1.0f;
        int   kk   = 0;
        if (resc) {
            int   src = __builtin_amdgcn_ds_bpermute(c << 2, __float_as_int(acc[0][0]));
            float c0  = __int_as_float(src);
            kk = (int)((__float_as_uint(c0) >> 23) & 0xff) - 127;
            rc = __uint_as_float((uint32_t)(127 - kk) << 23);
            if (mt != 0.0f) kSum += kk;
        }

        // epilogue: gamma_new = D * expE (*rc), to bf16 pairs, masked write
#pragma unroll
        for (int m = 0; m < 8; ++m) {
            float4 e4 = *(const float4*)(slot + 4 * m);
            if (resc) { e4.x *= rc; e4.y *= rc; e4.z *= rc; e4.w *= rc; }
            float x0 = acc[m][0] * e4.x, x1 = acc[m][1] * e4.y;
            float x2 = acc[m][2] * e4.z, x3 = acc[m][3] * e4.w;
            uint32_t p0, p1;
            asm("v_cvt_pk_bf16_f32 %0, %1, %2" : "=v"(p0) : "v"(x0), "v"(x1));
            asm("v_cvt_pk_bf16_f32 %0, %1, %2" : "=v"(p1) : "v"(x2), "v"(x3));
            if (mt != 0.0f)
                *(uint2*)&gam[c * GSTR + 8 * m + 2 * g] = make_uint2(p0, p1);
        }
        asm volatile("s_waitcnt lgkmcnt(0)");
        if (lane == 0) vfree[s] = t;
        // B fragments for next step
#pragma unroll
        for (int kt = 0; kt < 4; ++kt)
            Bf[kt].u4 = *(const uint4*)&gam[c * GSTR + 16 * kt + 4 * g];
    }

    // logZ per batch: log(sum gamma) + kSum*ln2
    float ssum = 0.f;
#pragma unroll
    for (int w = 0; w < 4; ++w) {
        uint4 u4 = *(const uint4*)&gam[c * GSTR + 16 * g + 4 * w];
        uint32_t uu[4] = {u4.x, u4.y, u4.z, u4.w};
#pragma unroll
        for (int k = 0; k < 4; ++k) {
            ssum += __uint_as_float(uu[k] << 16);
            ssum += __uint_as_float(uu[k] & 0xffff0000u);
        }
    }
    ssum += __shfl_xor(ssum, 16, 64);
    ssum += __shfl_xor(ssum, 32, 64);
    if (lane < 16) {
        float logZ = __logf(ssum) + (float)kSum * 0.69314718055994531f;
        atomicAdd(out, logZ * (1.0f / NBATCH));
    }
}

extern "C" void kernel_launch(void* const* d_in, const int* in_sizes, int n_in,
                              void* d_out, int out_size, void* d_ws, size_t ws_size,
                              hipStream_t stream) {
    const float* emissions   = (const float*)d_in[0];
    const float* transitions = (const float*)d_in[1];
    const int*   tags        = (const int*)d_in[2];
    const float* mask        = (const float*)d_in[3];
    float*       out         = (float*)d_out;

    hipMemsetAsync(out, 0, sizeof(float), stream);
    crf_kernel<<<80, 256, 0, stream>>>(emissions, transitions, tags, mask, out);
}

// Round 4
// 854.334 us; speedup vs baseline: 1.0404x; 1.0404x over previous
//
#include <hip/hip_runtime.h>
#include <stdint.h>

#define SEQ      1024
#define NT       128
#define NBATCH   256
#define RING     4
#define SLOT_F32 (64 * 36)   // per-slot: 64 lanes x (32 floats + 4 pad)

typedef float f32x4v __attribute__((ext_vector_type(4)));
using short8 = __attribute__((ext_vector_type(8))) short;
union B8 { uint4 u4; short8 s8; };

// blocks 0..15: recurrence (16 batches each; wave0 = consumer, waves1-3 = producers)
// blocks 16..79: score gathers (4 batches each, 1 wave per batch)
__global__ __launch_bounds__(256, 1) void crf_kernel(
    const float* __restrict__ emissions,   // [B, SEQ, NT]
    const float* __restrict__ transitions, // [NT, NT]
    const int*   __restrict__ tags,        // [B, SEQ]
    const float* __restrict__ mask,        // [B, SEQ]
    float* __restrict__ out)               // [1]
{
    const int blk = blockIdx.x;
    const int tid = threadIdx.x;

    if (blk >= 16) {
        // ---------------- score blocks ----------------
        int b    = (blk - 16) * 4 + (tid >> 6);
        int lane = tid & 63;
        const float* emb = emissions + (size_t)b * SEQ * NT;
        const int*   tgb = tags + (size_t)b * SEQ;
        const float* mkb = mask + (size_t)b * SEQ;
        float sc = 0.f;
        for (int t = lane; t < SEQ; t += 64) {
            int   tg = tgb[t];
            float mt = mkb[t];
            sc += emb[t * NT + tg] * mt;
            if (t >= 1) sc += transitions[tgb[t - 1] * NT + tg] * mt;
        }
#pragma unroll
        for (int o = 32; o > 0; o >>= 1) sc += __shfl_down(sc, o, 64);
        if (lane == 0) atomicAdd(out, -sc * (1.0f / NBATCH));
        return;
    }

    // ---------------- recurrence blocks ----------------
    __shared__ __align__(16) float ring[RING * SLOT_F32];   // 36864 B
    __shared__ int readyf[RING];
    __shared__ int freef[RING];

    const int wid   = tid >> 6;
    const int lane  = tid & 63;
    const int bbase = blk * 16;

    if (tid == 0) {
#pragma unroll
        for (int i = 0; i < RING; ++i) { readyf[i] = -1; freef[i] = -1; }
    }
    __syncthreads();

    volatile int* vready = readyf;
    volatile int* vfree  = freef;

    if (wid != 0) {
        // ---------- producers: steps t ≡ wid-1 (mod 3), exp(E_t) -> ring ----------
        const int bp = lane >> 2;     // batch 0..15
        const int tq = lane & 3;      // tag quarter (32 tags)
        const float* ebase = emissions + ((size_t)(bbase + bp) * SEQ) * NT + tq * 32;
        const int t0 = wid - 1;

#define PLOAD(Lx, t_) do { \
        const float* ep_ = ebase + (size_t)(t_) * NT; \
        _Pragma("unroll") for (int u = 0; u < 8; ++u) \
            Lx[u] = *(const float4*)(ep_ + u * 4); \
    } while (0)

#define PPROC(Lx, t_) do { \
        float4 W_[8]; \
        _Pragma("unroll") for (int u = 0; u < 8; ++u) { \
            W_[u].x = __expf(Lx[u].x); W_[u].y = __expf(Lx[u].y); \
            W_[u].z = __expf(Lx[u].z); W_[u].w = __expf(Lx[u].w); } \
        int s_ = (t_) & (RING - 1); \
        while (vfree[s_] < (t_) - RING) { __builtin_amdgcn_s_sleep(1); } \
        asm volatile("" ::: "memory"); \
        float* sp_ = ring + s_ * SLOT_F32; \
        _Pragma("unroll") for (int q = 0; q < 8; ++q) { \
            int a_ = (16 * (q & 3) + bp) * 36 + 8 * tq + 4 * (q >> 2); \
            *(float4*)(sp_ + a_) = W_[q]; } \
        asm volatile("s_waitcnt lgkmcnt(0)"); \
        if (lane == 0) vready[s_] = (t_); \
    } while (0)

        float4 L0[8], L1[8];
        PLOAD(L0, t0);
        PLOAD(L1, t0 + 3);   // t0+3 <= 5 < SEQ always

        for (int tt = t0; tt < SEQ; tt += 6) {
            PPROC(L0, tt);
            if (tt + 6 < SEQ) PLOAD(L0, tt + 6);
            if (tt + 3 < SEQ) {
                PPROC(L1, tt + 3);
                if (tt + 9 < SEQ) PLOAD(L1, tt + 9);
            }
        }
        return;
    }

    // ---------- consumer wave: the serial chain ----------
    const int g = lane >> 4;   // 0..3
    const int c = lane & 15;   // batch column

    // A = expT with tau-permuted k-rows, entire 128x128 in registers.
    // B slot (kt, k=8g+e) carries tag tau(kt,8g+e) = 16*(2kt+(e>>2)) + 4g + (e&3),
    // which is exactly where the D->cvt_pk words land, so B = recycled D.
    uint4 A[8][4];
#pragma unroll
    for (int m = 0; m < 8; ++m) {
#pragma unroll
        for (int kt = 0; kt < 4; ++kt) {
            uint32_t w[4];
#pragma unroll
            for (int wi = 0; wi < 4; ++wi) {
                int T0 = 16 * (2 * kt + (wi >> 1)) + 4 * g + 2 * (wi & 1);
                int jj = 16 * m + c;
                float f0 = __expf(transitions[T0 * NT + jj]);
                float f1 = __expf(transitions[(T0 + 1) * NT + jj]);
                asm("v_cvt_pk_bf16_f32 %0, %1, %2" : "=v"(w[wi]) : "v"(f0), "v"(f1));
            }
            A[m][kt] = make_uint4(w[0], w[1], w[2], w[3]);
        }
    }

    const float* mbase = mask + (size_t)(bbase + c) * SEQ;

    // t = 0: gamma0 = exp(E0), straight from slot 0 into B fragments
    B8 Bf[4];
    {
        while (vready[0] < 0) {}
        asm volatile("" ::: "memory");
        const float* slot = ring + lane * 36;
        uint32_t pk[8][2];
#pragma unroll
        for (int m = 0; m < 8; ++m) {
            float4 e4 = *(const float4*)(slot + 4 * m);
            asm("v_cvt_pk_bf16_f32 %0, %1, %2" : "=v"(pk[m][0]) : "v"(e4.x), "v"(e4.y));
            asm("v_cvt_pk_bf16_f32 %0, %1, %2" : "=v"(pk[m][1]) : "v"(e4.z), "v"(e4.w));
        }
#pragma unroll
        for (int kt = 0; kt < 4; ++kt)
            Bf[kt].u4 = make_uint4(pk[2*kt][0], pk[2*kt][1], pk[2*kt+1][0], pk[2*kt+1][1]);
        asm volatile("s_waitcnt lgkmcnt(0)");
        if (lane == 0) vfree[0] = 0;
    }
    // confirm slot for t = 1
    while (vready[1] < 1) {}
    asm volatile("" ::: "memory");

    int   kSum   = 0;
    float mt_cur = mbase[1];
    const f32x4v zero4 = {0.f, 0.f, 0.f, 0.f};

    for (int t = 1; t < SEQ; ++t) {
        const int s = t & (RING - 1);
        const float* slot = ring + s * SLOT_F32 + lane * 36;

        // issue exp(E_t) reads early (slot confirmed last iteration)
        float4 e4[8];
#pragma unroll
        for (int m = 0; m < 8; ++m) e4[m] = *(const float4*)(slot + 4 * m);

        // rescale factor from PREVIOUS gamma's tag0 (off the critical path)
        const bool resc = ((t & 3) == 0);
        int   kk  = 0;
        float rcf = 1.0f;
        if (resc) {
            int v = __builtin_amdgcn_ds_bpermute(c << 2, (int)Bf[0].u4.x);
            int ebits = (v >> 7) & 0xff;          // bf16 exponent of gamma[0]
            kk  = ebits - 127;
            rcf = __uint_as_float((uint32_t)(254 - ebits) << 23);  // 2^{-kk}
        }

        // 32 MFMAs, kt-major: 8 independent chains interleaved -> pipelined
        f32x4v acc[8];
#pragma unroll
        for (int m = 0; m < 8; ++m) {
            B8 a; a.u4 = A[m][0];
            acc[m] = __builtin_amdgcn_mfma_f32_16x16x32_bf16(a.s8, Bf[0].s8, zero4, 0, 0, 0);
        }
#pragma unroll
        for (int kt = 1; kt < 4; ++kt) {
#pragma unroll
            for (int m = 0; m < 8; ++m) {
                B8 a; a.u4 = A[m][kt];
                acc[m] = __builtin_amdgcn_mfma_f32_16x16x32_bf16(a.s8, Bf[kt].s8, acc[m], 0, 0, 0);
            }
        }

        // poll next slot while the MFMA pipe drains
        if (t + 1 < SEQ) {
            while (vready[(t + 1) & (RING - 1)] < t + 1) {}
            asm volatile("" ::: "memory");
        }

        float mt = mt_cur;
        mt_cur = mbase[t + 1 < SEQ ? t + 1 : SEQ - 1];
        const bool upd = (mt != 0.0f);
        if (resc && upd) kSum += kk;

        // epilogue: gamma_new = D * expE (* rc) -> bf16 pairs -> next B frags
        uint32_t pk[8][2];
#pragma unroll
        for (int m = 0; m < 8; ++m) {
            float4 e = e4[m];
            if (resc) { e.x *= rcf; e.y *= rcf; e.z *= rcf; e.w *= rcf; }
            float x0 = acc[m][0] * e.x, x1 = acc[m][1] * e.y;
            float x2 = acc[m][2] * e.z, x3 = acc[m][3] * e.w;
            asm("v_cvt_pk_bf16_f32 %0, %1, %2" : "=v"(pk[m][0]) : "v"(x0), "v"(x1));
            asm("v_cvt_pk_bf16_f32 %0, %1, %2" : "=v"(pk[m][1]) : "v"(x2), "v"(x3));
        }
#pragma unroll
        for (int kt = 0; kt < 4; ++kt) {
            uint4 nb = make_uint4(pk[2*kt][0], pk[2*kt][1], pk[2*kt+1][0], pk[2*kt+1][1]);
            if (upd) Bf[kt].u4 = nb;     // masked batches keep old gamma
        }

        asm volatile("s_waitcnt lgkmcnt(0)");
        if (lane == 0) vfree[s] = t;
    }

    // logZ per batch: log(sum_tags gamma) + kSum*ln2
    float ssum = 0.f;
#pragma unroll
    for (int kt = 0; kt < 4; ++kt) {
        uint32_t uu[4] = {Bf[kt].u4.x, Bf[kt].u4.y, Bf[kt].u4.z, Bf[kt].u4.w};
#pragma unroll
        for (int k = 0; k < 4; ++k) {
            ssum += __uint_as_float(uu[k] << 16);
            ssum += __uint_as_float(uu[k] & 0xffff0000u);
        }
    }
    ssum += __shfl_xor(ssum, 16, 64);
    ssum += __shfl_xor(ssum, 32, 64);
    if (lane < 16) {
        float logZ = __logf(ssum) + (float)kSum * 0.69314718055994531f;
        atomicAdd(out, logZ * (1.0f / NBATCH));
    }
}

extern "C" void kernel_launch(void* const* d_in, const int* in_sizes, int n_in,
                              void* d_out, int out_size, void* d_ws, size_t ws_size,
                              hipStream_t stream) {
    const float* emissions   = (const float*)d_in[0];
    const float* transitions = (const float*)d_in[1];
    const int*   tags        = (const int*)d_in[2];
    const float* mask        = (const float*)d_in[3];
    float*       out         = (float*)d_out;

    hipMemsetAsync(out, 0, sizeof(float), stream);
    crf_kernel<<<80, 256, 0, stream>>>(emissions, transitions, tags, mask, out);
}